// Round 1
// 740.822 us; speedup vs baseline: 1.0284x; 1.0284x over previous
//
#include <hip/hip_runtime.h>
#include <hip/hip_fp16.h>

#define NN 8192
#define FF 128
#define HH 64
#define GG 4
#define CONV_TH2 1e-10f

typedef _Float16 half8 __attribute__((ext_vector_type(8)));
typedef float floatx4 __attribute__((ext_vector_type(4)));

// ws layout (bytes)
#define OFF_WIU  134217728ull                  // Lh: [8192][8192] fp16 = 128 MB
#define OFF_LIN  142606336ull                  // wiu: [8192][256] fp32 = 8 MB
#define OFF_CP   146800640ull                  // lin_t: [256][8192] fp16 = 4 MB
#define OFF_META 180355072ull                  // C_part: [4][8192][256] fp32 = 32 MB

__device__ __forceinline__ void load16(const void* g, void* l) {
  __builtin_amdgcn_global_load_lds((const __attribute__((address_space(1))) void*)g,
                                   (__attribute__((address_space(3))) void*)l,
                                   16, 0, 0);
}

// fp32 L -> fp16 Lh; block 0 also zeroes the diffsq scoreboard (replaces k_init)
__global__ __launch_bounds__(256) void k_convert(const float* __restrict__ L,
                                                 _Float16* __restrict__ Lh,
                                                 float* __restrict__ diffsq) {
  if (blockIdx.x == 0 && threadIdx.x < 32) diffsq[threadIdx.x] = 0.f;
  size_t i = ((size_t)blockIdx.x * 256 + threadIdx.x) * 8;
  float4 a = *(const float4*)(L + i);
  float4 b = *(const float4*)(L + i + 4);
  half8 h;
  h[0] = (_Float16)a.x; h[1] = (_Float16)a.y; h[2] = (_Float16)a.z; h[3] = (_Float16)a.w;
  h[4] = (_Float16)b.x; h[5] = (_Float16)b.y; h[6] = (_Float16)b.z; h[7] = (_Float16)b.w;
  *(half8*)(Lh + i) = h;
}

// wiu = X @ W_ih[g]^T ; hx1 = tanh(wiu) ; diff1 = ||hx1||^2 ; lin_t for iter 2
__global__ __launch_bounds__(256) void k_wiu(const float* __restrict__ X,
    const float* __restrict__ Wih, const float* __restrict__ Whh,
    float* __restrict__ wiu, float* __restrict__ hx,
    _Float16* __restrict__ lin_t, float* __restrict__ diffsq) {
  __shared__ __align__(16) float smem[2 * 64 * 128];   // 64 KB
  float* Xs = smem;              // [64][128], XOR-swizzled float4 chunks
  float* Ws = smem + 64 * 128;
  const int bx = blockIdx.x, g = blockIdx.y;
  const int t = threadIdx.x;
  const int m0 = bx * 64;
  #pragma unroll
  for (int p = 0; p < 8; ++p) {
    int idx = p * 256 + t;       // float4 id 0..2047
    int row = idx >> 5;
    int c4 = idx & 31;
    int sw = (c4 ^ (row >> 2)) & 31;
    float4 xv = *(const float4*)(X + (size_t)(m0 + row) * FF + c4 * 4);
    *(float4*)(Xs + row * 128 + sw * 4) = xv;
    float4 wv = *(const float4*)(Wih + (size_t)g * HH * FF + (size_t)row * FF + c4 * 4);
    *(float4*)(Ws + row * 128 + sw * 4) = wv;
  }
  __syncthreads();
  const int tc = t & 15, tm = t >> 4;
  float acc[4][4];
  #pragma unroll
  for (int r = 0; r < 4; ++r)
    #pragma unroll
    for (int s = 0; s < 4; ++s) acc[r][s] = 0.f;
  for (int f4 = 0; f4 < 32; ++f4) {
    float4 xv[4], wv[4];
    #pragma unroll
    for (int r = 0; r < 4; ++r) {
      int m = tm * 4 + r;
      xv[r] = *(const float4*)(Xs + m * 128 + (((f4 ^ (m >> 2)) & 31) * 4));
    }
    #pragma unroll
    for (int s = 0; s < 4; ++s) {
      int c = tc * 4 + s;
      wv[s] = *(const float4*)(Ws + c * 128 + (((f4 ^ (c >> 2)) & 31) * 4));
    }
    #pragma unroll
    for (int r = 0; r < 4; ++r)
      #pragma unroll
      for (int s = 0; s < 4; ++s)
        acc[r][s] += xv[r].x * wv[s].x + xv[r].y * wv[s].y +
                     xv[r].z * wv[s].z + xv[r].w * wv[s].w;
  }
  __syncthreads();               // done with Xs/Ws; alias below
  float* hxs = smem;             // [64][65]
  float* Whs = smem + 64 * 65;   // [64][65]
  float diffp = 0.f;
  #pragma unroll
  for (int r = 0; r < 4; ++r) {
    int ml = tm * 4 + r;
    size_t off = (size_t)(m0 + ml) * 256 + g * 64 + tc * 4;
    float4 wv = make_float4(acc[r][0], acc[r][1], acc[r][2], acc[r][3]);
    *(float4*)(wiu + off) = wv;
    float4 hv;
    hv.x = tanhf(wv.x); hv.y = tanhf(wv.y); hv.z = tanhf(wv.z); hv.w = tanhf(wv.w);
    *(float4*)(hx + off) = hv;
    hxs[ml * 65 + tc * 4 + 0] = hv.x;
    hxs[ml * 65 + tc * 4 + 1] = hv.y;
    hxs[ml * 65 + tc * 4 + 2] = hv.z;
    hxs[ml * 65 + tc * 4 + 3] = hv.w;
    diffp += hv.x * hv.x + hv.y * hv.y + hv.z * hv.z + hv.w * hv.w;
  }
  #pragma unroll
  for (int p = 0; p < 16; ++p) {
    int idx = p * 256 + t;
    Whs[(idx >> 6) * 65 + (idx & 63)] = Whh[(size_t)g * HH * HH + idx];
  }
  for (int o = 32; o; o >>= 1) diffp += __shfl_down(diffp, o);
  if ((t & 63) == 0) atomicAdd(diffsq + g, diffp);
  __syncthreads();
  const int ml = t & 63, wv_ = t >> 6;
  float lacc[16];
  #pragma unroll
  for (int i = 0; i < 16; ++i) lacc[i] = 0.f;
  for (int h = 0; h < 64; ++h) {
    float xh = hxs[ml * 65 + h];
    #pragma unroll
    for (int i = 0; i < 16; ++i)
      lacc[i] += xh * Whs[(wv_ + 4 * i) * 65 + h];
  }
  #pragma unroll
  for (int i = 0; i < 16; ++i)
    lin_t[(size_t)(g * 64 + wv_ + 4 * i) * NN + m0 + ml] = (_Float16)lacc[i];
}

// ---- k_gemm: 2-phase double-buffered pipeline -------------------------------
// C_part[bz] = Lh[m0:m0+128, k0:k0+2048] @ lin_t^T[., c0:c0+128]
// LDS: 2 buffers x (As [128][64] | Bs [128][64]) fp16, chunk-swizzled = 64 KB.
// Per K-round: STAGE(next tile -> other buffer) issued BEFORE compute(current),
// single __syncthreads() per round (its implicit vmcnt(0) is the pipeline drain,
// placed AFTER compute so the load latency hides under the MFMAs).

__device__ __forceinline__ void g_stage(const _Float16* ga, const _Float16* gb,
                                        _Float16* lbase) {
  #pragma unroll
  for (int i = 0; i < 4; ++i) {
    load16(ga + (size_t)i * 32 * NN, lbase + i * 2048);          // A chunks
    load16(gb + (size_t)i * 32 * NN, lbase + 8192 + i * 2048);   // B chunks
  }
}

__device__ __forceinline__ void g_compute(const _Float16* sbase,
    const int (&aoffs)[2][4], const int (&boffs)[2][4], floatx4 (&acc)[4][4]) {
  #pragma unroll
  for (int ks = 0; ks < 2; ++ks) {
    half8 af[4], bf[4];
    #pragma unroll
    for (int mt = 0; mt < 4; ++mt) af[mt] = *(const half8*)(sbase + aoffs[ks][mt]);
    #pragma unroll
    for (int nt = 0; nt < 4; ++nt) bf[nt] = *(const half8*)(sbase + 8192 + boffs[ks][nt]);
    #pragma unroll
    for (int mt = 0; mt < 4; ++mt)
      #pragma unroll
      for (int nt = 0; nt < 4; ++nt)
        acc[mt][nt] = __builtin_amdgcn_mfma_f32_16x16x32_f16(af[mt], bf[nt], acc[mt][nt], 0, 0, 0);
  }
}

__global__ __launch_bounds__(256) void k_gemm(const _Float16* __restrict__ A,
    const _Float16* __restrict__ Bt, float* __restrict__ Cp) {
  __shared__ __align__(16) _Float16 smem[32768];   // 64 KB, two 16384-half buffers
  const int bx = blockIdx.x;   // m block (128 rows)
  const int by = blockIdx.y;   // n block (128 cols)
  const int bz = blockIdx.z;   // k chunk (2048)
  const int t = threadIdx.x;
  const int lane = t & 63, wid = t >> 6;
  const int wr = wid >> 1, wc = wid & 1;
  const int l15 = lane & 15, quad = lane >> 4;
  const size_t m0 = (size_t)bx * 128;
  const size_t c0 = (size_t)by * 128;
  const size_t k0 = (size_t)bz * 2048;

  // staging addresses: chunk ch = i*256 + t; row = i*32 + (t>>3);
  // swizzled k-chunk j = (t&7) ^ ((t>>3)&7)  (independent of i)
  const int r_ = t >> 3;
  const int j_ = (t & 7) ^ (r_ & 7);
  const _Float16* ga = A  + (m0 + r_) * NN + k0 + (size_t)j_ * 8;
  const _Float16* gb = Bt + (c0 + r_) * NN + k0 + (size_t)j_ * 8;
  _Float16* lb = &smem[t * 8];   // wave-uniform base + lane*16B (global_load_lds req.)

  // fragment LDS offsets (halves, within a buffer), constant across rounds
  int aoffs[2][4], boffs[2][4];
  #pragma unroll
  for (int ks = 0; ks < 2; ++ks) {
    #pragma unroll
    for (int mt = 0; mt < 4; ++mt) {
      int m = wr * 64 + mt * 16 + l15;
      aoffs[ks][mt] = m * 64 + (((ks * 4 + quad) ^ (m & 7)) * 8);
    }
    #pragma unroll
    for (int nt = 0; nt < 4; ++nt) {
      int n = wc * 64 + nt * 16 + l15;
      boffs[ks][nt] = n * 64 + (((ks * 4 + quad) ^ (n & 7)) * 8);
    }
  }
  floatx4 acc[4][4];
  #pragma unroll
  for (int mt = 0; mt < 4; ++mt)
    #pragma unroll
    for (int nt = 0; nt < 4; ++nt)
      acc[mt][nt] = (floatx4){0.f, 0.f, 0.f, 0.f};

  // prologue: fill buffer 0 (round 0)
  g_stage(ga, gb, lb); ga += 64; gb += 64;
  __syncthreads();
  // 32 rounds total, unrolled in pairs so buffer selection is compile-time
  for (int it2 = 0; it2 < 15; ++it2) {
    g_stage(ga, gb, lb + 16384); ga += 64; gb += 64;   // stage odd round -> buf1
    g_compute(smem, aoffs, boffs, acc);                // compute even round (buf0)
    __syncthreads();
    g_stage(ga, gb, lb); ga += 64; gb += 64;           // stage even round -> buf0
    g_compute(smem + 16384, aoffs, boffs, acc);        // compute odd round (buf1)
    __syncthreads();
  }
  g_stage(ga, gb, lb + 16384);                         // round 31 -> buf1
  g_compute(smem, aoffs, boffs, acc);                  // round 30 (buf0)
  __syncthreads();
  g_compute(smem + 16384, aoffs, boffs, acc);          // round 31 (buf1)

  // write partial C: C/D layout col=lane&15, row=quad*4+reg
  float* Cb = Cp + (size_t)bz * NN * 256;
  #pragma unroll
  for (int mt = 0; mt < 4; ++mt) {
    #pragma unroll
    for (int nt = 0; nt < 4; ++nt) {
      size_t gm = m0 + wr * 64 + mt * 16 + quad * 4;
      size_t gc = c0 + wc * 64 + nt * 16 + l15;
      #pragma unroll
      for (int rg = 0; rg < 4; ++rg)
        Cb[(gm + rg) * 256 + gc] = acc[mt][nt][rg];
    }
  }
}

// sum split-K partials, new=tanh(wiu+C), mask with done (derived inline from the
// diffsq history -- replaces the k_done micro-kernels), diff^2, lin for next iter
__global__ __launch_bounds__(256) void k_post(const float* __restrict__ Cp,
    const float* __restrict__ wiu, const float* __restrict__ Whh,
    float* __restrict__ hx, _Float16* __restrict__ lin_t,
    float* __restrict__ diffsq, int it, int write_lin) {
  __shared__ float hxs[64 * 65];
  __shared__ float Whs[64 * 65];
  const int bx = blockIdx.x, g = blockIdx.y, t = threadIdx.x;
  const int m0 = bx * 64;
  const int tcol = t & 15, trow = t >> 4;
  // done[g] = OR over previous steps of (||diff||^2 < TH^2); diffsq[j*GG+g] was
  // fully accumulated by the kernel that computed step j (stream-serialized).
  int dn = 0;
  #pragma unroll
  for (int j = 0; j < 4; ++j)
    if (j < it) dn |= (diffsq[j * GG + g] < CONV_TH2) ? 1 : 0;
  float diffp = 0.f;
  #pragma unroll
  for (int p = 0; p < 4; ++p) {
    int ml = p * 16 + trow;
    size_t off = (size_t)(m0 + ml) * 256 + g * 64 + tcol * 4;
    float4 s  = *(const float4*)(Cp + off);
    float4 q1 = *(const float4*)(Cp + (size_t)1 * NN * 256 + off);
    float4 q2 = *(const float4*)(Cp + (size_t)2 * NN * 256 + off);
    float4 q3 = *(const float4*)(Cp + (size_t)3 * NN * 256 + off);
    s.x += q1.x + q2.x + q3.x; s.y += q1.y + q2.y + q3.y;
    s.z += q1.z + q2.z + q3.z; s.w += q1.w + q2.w + q3.w;
    float4 wv = *(const float4*)(wiu + off);
    float4 old = *(const float4*)(hx + off);
    float4 nv;
    nv.x = tanhf(wv.x + s.x); nv.y = tanhf(wv.y + s.y);
    nv.z = tanhf(wv.z + s.z); nv.w = tanhf(wv.w + s.w);
    float4 ov;
    ov.x = dn ? old.x : nv.x; ov.y = dn ? old.y : nv.y;
    ov.z = dn ? old.z : nv.z; ov.w = dn ? old.w : nv.w;
    *(float4*)(hx + off) = ov;
    float dx = nv.x - old.x, dy = nv.y - old.y, dz = nv.z - old.z, dw = nv.w - old.w;
    diffp += dx * dx + dy * dy + dz * dz + dw * dw;
    hxs[ml * 65 + tcol * 4 + 0] = ov.x;
    hxs[ml * 65 + tcol * 4 + 1] = ov.y;
    hxs[ml * 65 + tcol * 4 + 2] = ov.z;
    hxs[ml * 65 + tcol * 4 + 3] = ov.w;
  }
  if (write_lin) {
    #pragma unroll
    for (int p = 0; p < 16; ++p) {
      int idx = p * 256 + t;
      Whs[(idx >> 6) * 65 + (idx & 63)] = Whh[(size_t)g * HH * HH + idx];
    }
  }
  for (int o = 32; o; o >>= 1) diffp += __shfl_down(diffp, o);
  if ((t & 63) == 0) atomicAdd(diffsq + it * GG + g, diffp);
  if (!write_lin) return;
  __syncthreads();
  const int ml = t & 63, wv_ = t >> 6;
  float lacc[16];
  #pragma unroll
  for (int i = 0; i < 16; ++i) lacc[i] = 0.f;
  for (int h = 0; h < 64; ++h) {
    float xh = hxs[ml * 65 + h];
    #pragma unroll
    for (int i = 0; i < 16; ++i)
      lacc[i] += xh * Whs[(wv_ + 4 * i) * 65 + h];
  }
  #pragma unroll
  for (int i = 0; i < 16; ++i)
    lin_t[(size_t)(g * 64 + wv_ + 4 * i) * NN + m0 + ml] = (_Float16)lacc[i];
}

extern "C" void kernel_launch(void* const* d_in, const int* in_sizes, int n_in,
                              void* d_out, int out_size, void* d_ws, size_t ws_size,
                              hipStream_t stream) {
  const float* X   = (const float*)d_in[0];
  const float* L   = (const float*)d_in[1];
  const float* Wih = (const float*)d_in[2];
  const float* Whh = (const float*)d_in[3];
  float* out = (float*)d_out;
  char* ws = (char*)d_ws;
  _Float16* Lh    = (_Float16*)ws;
  float*    wiu   = (float*)(ws + OFF_WIU);
  _Float16* lin_t = (_Float16*)(ws + OFF_LIN);
  float*    Cp    = (float*)(ws + OFF_CP);
  float*    diffsq = (float*)(ws + OFF_META);

  k_convert<<<32768, 256, 0, stream>>>(L, Lh, diffsq);
  k_wiu<<<dim3(128, 4), 256, 0, stream>>>(X, Wih, Whh, wiu, out, lin_t, diffsq);
  for (int it = 1; it <= 4; ++it) {
    k_gemm<<<dim3(64, 2, 4), 256, 0, stream>>>(Lh, lin_t, Cp);
    k_post<<<dim3(128, 4), 256, 0, stream>>>(Cp, wiu, Whh, out, lin_t, diffsq,
                                             it, (it < 4) ? 1 : 0);
  }
}

// Round 2
// 721.656 us; speedup vs baseline: 1.0557x; 1.0266x over previous
//
#include <hip/hip_runtime.h>
#include <hip/hip_fp16.h>

#define NN 8192
#define FF 128
#define HH 64
#define GG 4
#define CONV_TH2 1e-10f

typedef _Float16 half8 __attribute__((ext_vector_type(8)));
typedef float floatx4 __attribute__((ext_vector_type(4)));

// ws layout (bytes)
#define OFF_WIU  134217728ull                  // Lh: [8192][8192] fp16 = 128 MB
#define OFF_LIN  142606336ull                  // wiu: [8192][256] fp32 = 8 MB
#define OFF_CP   146800640ull                  // lin_t: [256][8192] fp16 = 4 MB
#define OFF_META 180355072ull                  // C_part: [4][8192][256] fp32 = 32 MB

__device__ __forceinline__ void load16(const void* g, void* l) {
  __builtin_amdgcn_global_load_lds((const __attribute__((address_space(1))) void*)g,
                                   (__attribute__((address_space(3))) void*)l,
                                   16, 0, 0);
}

#define BAR()  __builtin_amdgcn_s_barrier()
#define WAITV(N) asm volatile("s_waitcnt vmcnt(" #N ")" ::: "memory")
#define WAITL()  asm volatile("s_waitcnt lgkmcnt(0)" ::: "memory")

// fp32 L -> fp16 Lh; block 0 also zeroes the diffsq scoreboard
__global__ __launch_bounds__(256) void k_convert(const float* __restrict__ L,
                                                 _Float16* __restrict__ Lh,
                                                 float* __restrict__ diffsq) {
  if (blockIdx.x == 0 && threadIdx.x < 32) diffsq[threadIdx.x] = 0.f;
  size_t i = ((size_t)blockIdx.x * 256 + threadIdx.x) * 8;
  float4 a = *(const float4*)(L + i);
  float4 b = *(const float4*)(L + i + 4);
  half8 h;
  h[0] = (_Float16)a.x; h[1] = (_Float16)a.y; h[2] = (_Float16)a.z; h[3] = (_Float16)a.w;
  h[4] = (_Float16)b.x; h[5] = (_Float16)b.y; h[6] = (_Float16)b.z; h[7] = (_Float16)b.w;
  *(half8*)(Lh + i) = h;
}

// wiu = X @ W_ih[g]^T ; hx1 = tanh(wiu) ; diff1 = ||hx1||^2 ; lin_t for iter 2
__global__ __launch_bounds__(256) void k_wiu(const float* __restrict__ X,
    const float* __restrict__ Wih, const float* __restrict__ Whh,
    float* __restrict__ wiu, float* __restrict__ hx,
    _Float16* __restrict__ lin_t, float* __restrict__ diffsq) {
  __shared__ __align__(16) float smem[2 * 64 * 128];   // 64 KB
  float* Xs = smem;              // [64][128], XOR-swizzled float4 chunks
  float* Ws = smem + 64 * 128;
  const int bx = blockIdx.x, g = blockIdx.y;
  const int t = threadIdx.x;
  const int m0 = bx * 64;
  #pragma unroll
  for (int p = 0; p < 8; ++p) {
    int idx = p * 256 + t;       // float4 id 0..2047
    int row = idx >> 5;
    int c4 = idx & 31;
    int sw = (c4 ^ (row >> 2)) & 31;
    float4 xv = *(const float4*)(X + (size_t)(m0 + row) * FF + c4 * 4);
    *(float4*)(Xs + row * 128 + sw * 4) = xv;
    float4 wv = *(const float4*)(Wih + (size_t)g * HH * FF + (size_t)row * FF + c4 * 4);
    *(float4*)(Ws + row * 128 + sw * 4) = wv;
  }
  __syncthreads();
  const int tc = t & 15, tm = t >> 4;
  float acc[4][4];
  #pragma unroll
  for (int r = 0; r < 4; ++r)
    #pragma unroll
    for (int s = 0; s < 4; ++s) acc[r][s] = 0.f;
  for (int f4 = 0; f4 < 32; ++f4) {
    float4 xv[4], wv[4];
    #pragma unroll
    for (int r = 0; r < 4; ++r) {
      int m = tm * 4 + r;
      xv[r] = *(const float4*)(Xs + m * 128 + (((f4 ^ (m >> 2)) & 31) * 4));
    }
    #pragma unroll
    for (int s = 0; s < 4; ++s) {
      int c = tc * 4 + s;
      wv[s] = *(const float4*)(Ws + c * 128 + (((f4 ^ (c >> 2)) & 31) * 4));
    }
    #pragma unroll
    for (int r = 0; r < 4; ++r)
      #pragma unroll
      for (int s = 0; s < 4; ++s)
        acc[r][s] += xv[r].x * wv[s].x + xv[r].y * wv[s].y +
                     xv[r].z * wv[s].z + xv[r].w * wv[s].w;
  }
  __syncthreads();               // done with Xs/Ws; alias below
  float* hxs = smem;             // [64][65]
  float* Whs = smem + 64 * 65;   // [64][65]
  float diffp = 0.f;
  #pragma unroll
  for (int r = 0; r < 4; ++r) {
    int ml = tm * 4 + r;
    size_t off = (size_t)(m0 + ml) * 256 + g * 64 + tc * 4;
    float4 wv = make_float4(acc[r][0], acc[r][1], acc[r][2], acc[r][3]);
    *(float4*)(wiu + off) = wv;
    float4 hv;
    hv.x = tanhf(wv.x); hv.y = tanhf(wv.y); hv.z = tanhf(wv.z); hv.w = tanhf(wv.w);
    *(float4*)(hx + off) = hv;
    hxs[ml * 65 + tc * 4 + 0] = hv.x;
    hxs[ml * 65 + tc * 4 + 1] = hv.y;
    hxs[ml * 65 + tc * 4 + 2] = hv.z;
    hxs[ml * 65 + tc * 4 + 3] = hv.w;
    diffp += hv.x * hv.x + hv.y * hv.y + hv.z * hv.z + hv.w * hv.w;
  }
  #pragma unroll
  for (int p = 0; p < 16; ++p) {
    int idx = p * 256 + t;
    Whs[(idx >> 6) * 65 + (idx & 63)] = Whh[(size_t)g * HH * HH + idx];
  }
  for (int o = 32; o; o >>= 1) diffp += __shfl_down(diffp, o);
  if ((t & 63) == 0) atomicAdd(diffsq + g, diffp);
  __syncthreads();
  const int ml = t & 63, wv_ = t >> 6;
  float lacc[16];
  #pragma unroll
  for (int i = 0; i < 16; ++i) lacc[i] = 0.f;
  for (int h = 0; h < 64; ++h) {
    float xh = hxs[ml * 65 + h];
    #pragma unroll
    for (int i = 0; i < 16; ++i)
      lacc[i] += xh * Whs[(wv_ + 4 * i) * 65 + h];
  }
  #pragma unroll
  for (int i = 0; i < 16; ++i)
    lin_t[(size_t)(g * 64 + wv_ + 4 * i) * NN + m0 + ml] = (_Float16)lacc[i];
}

// ---- k_gemm: BM=128 x BN=256, BK=64, depth-3 counted-vmcnt pipeline ---------
// C_part[bz] = Lh[m0:m0+128, k0:k0+2048] @ lin_t^T  (all 256 cols per block)
// 512 threads = 8 waves (2 M x 4 N), wave tile 64x64, acc 4x4 frags.
// LDS: 3 buffers x (As[128][64] 16KB + Bs[256][64] 32KB) = 144 KB -> 1 blk/CU.
// Per round t: stage(t+2) -> buf[(t+2)%3]; s_waitcnt vmcnt(12) (2 stages of 6
// loads stay IN FLIGHT across the barrier -- T4); raw s_barrier; compute(t);
// lgkmcnt(0); s_barrier. Buffer indices are all compile-time (groups of 3).

__device__ __forceinline__ void g_stage(const _Float16* ga, const _Float16* gb,
                                        _Float16* da, _Float16* db) {
  load16(ga,            da);                 // A rows t>>3       (2 chunks)
  load16(ga + 64 * NN,  da + 4096);          // A rows 64+(t>>3)
  load16(gb,            db);                 // B rows t>>3       (4 chunks)
  load16(gb + 64 * NN,  db + 4096);
  load16(gb + 128 * NN, db + 8192);
  load16(gb + 192 * NN, db + 12288);
}

__device__ __forceinline__ void g_compute(const _Float16* sb,
    const int (&aoffs)[2][4], const int (&boffs)[2][4], floatx4 (&acc)[4][4]) {
  #pragma unroll
  for (int ks = 0; ks < 2; ++ks) {
    half8 af[4], bf[4];
    #pragma unroll
    for (int mt = 0; mt < 4; ++mt) af[mt] = *(const half8*)(sb + aoffs[ks][mt]);
    #pragma unroll
    for (int nt = 0; nt < 4; ++nt) bf[nt] = *(const half8*)(sb + 8192 + boffs[ks][nt]);
    #pragma unroll
    for (int mt = 0; mt < 4; ++mt)
      #pragma unroll
      for (int nt = 0; nt < 4; ++nt)
        acc[mt][nt] = __builtin_amdgcn_mfma_f32_16x16x32_f16(af[mt], bf[nt], acc[mt][nt], 0, 0, 0);
  }
}

__global__ __launch_bounds__(512, 2) void k_gemm(const _Float16* __restrict__ A,
    const _Float16* __restrict__ Bt, float* __restrict__ Cp) {
  __shared__ __align__(16) _Float16 smem[3 * 24576];   // 144 KB
  const int bx = blockIdx.x;   // m block (128 rows)
  const int bz = blockIdx.y;   // k chunk (2048)
  const int t = threadIdx.x;
  const int lane = t & 63, wid = t >> 6;
  const int wr = wid >> 2, wc = wid & 3;
  const int l15 = lane & 15, quad = lane >> 4;
  const size_t m0 = (size_t)bx * 128;
  const size_t k0 = (size_t)bz * 2048;

  // staging: chunk ch = i*512 + t; row = ch>>3; swizzled k-chunk j = (t&7)^((t>>3)&7)
  const int r_ = t >> 3;
  const int j_ = (t & 7) ^ (r_ & 7);
  const _Float16* ga = A  + (m0 + r_) * NN + k0 + (size_t)j_ * 8;
  const _Float16* gb = Bt + (size_t)r_ * NN + k0 + (size_t)j_ * 8;
  // per-thread LDS staging dests (wave-uniform base + lane*16B within each wave)
  _Float16* dA0 = smem + t * 8;                 _Float16* dB0 = dA0 + 8192;
  _Float16* dA1 = smem + 24576 + t * 8;         _Float16* dB1 = dA1 + 8192;
  _Float16* dA2 = smem + 49152 + t * 8;         _Float16* dB2 = dA2 + 8192;
  const _Float16* sb0 = smem;
  const _Float16* sb1 = smem + 24576;
  const _Float16* sb2 = smem + 49152;

  // fragment LDS offsets (halves, within a buffer), constant across rounds
  int aoffs[2][4], boffs[2][4];
  #pragma unroll
  for (int ks = 0; ks < 2; ++ks) {
    #pragma unroll
    for (int mt = 0; mt < 4; ++mt) {
      int m = wr * 64 + mt * 16 + l15;
      aoffs[ks][mt] = m * 64 + (((ks * 4 + quad) ^ (m & 7)) * 8);
    }
    #pragma unroll
    for (int nt = 0; nt < 4; ++nt) {
      int n = wc * 64 + nt * 16 + l15;
      boffs[ks][nt] = n * 64 + (((ks * 4 + quad) ^ (n & 7)) * 8);
    }
  }
  floatx4 acc[4][4];
  #pragma unroll
  for (int mt = 0; mt < 4; ++mt)
    #pragma unroll
    for (int nt = 0; nt < 4; ++nt)
      acc[mt][nt] = (floatx4){0.f, 0.f, 0.f, 0.f};

  // prologue: stage rounds 0 (buf0), 1 (buf1)
  g_stage(ga, gb, dA0, dB0); ga += 64; gb += 64;
  g_stage(ga, gb, dA1, dB1); ga += 64; gb += 64;
  // 32 rounds; rounds 0..29 in 10 groups of 3 (buffer ids compile-time)
  #pragma unroll 1
  for (int grp = 0; grp < 10; ++grp) {
    g_stage(ga, gb, dA2, dB2); ga += 64; gb += 64;   // stage t+2
    WAITV(12); BAR();                                // round-t data landed (2 stages in flight)
    g_compute(sb0, aoffs, boffs, acc);
    WAITL(); BAR();                                  // safe to overwrite buf0 next
    g_stage(ga, gb, dA0, dB0); ga += 64; gb += 64;
    WAITV(12); BAR();
    g_compute(sb1, aoffs, boffs, acc);
    WAITL(); BAR();
    g_stage(ga, gb, dA1, dB1); ga += 64; gb += 64;
    WAITV(12); BAR();
    g_compute(sb2, aoffs, boffs, acc);
    WAITL(); BAR();
  }
  // epilogue: rounds 30 (buf0), 31 (buf1); drain 6 -> 0
  WAITV(6); BAR();
  g_compute(sb0, aoffs, boffs, acc);
  WAITV(0); BAR();
  g_compute(sb1, aoffs, boffs, acc);

  // write partial C: C/D layout col=lane&15, row=quad*4+reg
  float* Cb = Cp + (size_t)bz * NN * 256;
  #pragma unroll
  for (int mt = 0; mt < 4; ++mt) {
    #pragma unroll
    for (int nt = 0; nt < 4; ++nt) {
      size_t gm = m0 + wr * 64 + mt * 16 + quad * 4;
      size_t gc = (size_t)wc * 64 + nt * 16 + l15;
      #pragma unroll
      for (int rg = 0; rg < 4; ++rg)
        Cb[(gm + rg) * 256 + gc] = acc[mt][nt][rg];
    }
  }
}

// sum split-K partials, new=tanh(wiu+C), mask with done (derived inline from the
// diffsq history), diff^2, lin for next iter
__global__ __launch_bounds__(256) void k_post(const float* __restrict__ Cp,
    const float* __restrict__ wiu, const float* __restrict__ Whh,
    float* __restrict__ hx, _Float16* __restrict__ lin_t,
    float* __restrict__ diffsq, int it, int write_lin) {
  __shared__ float hxs[64 * 65];
  __shared__ float Whs[64 * 65];
  const int bx = blockIdx.x, g = blockIdx.y, t = threadIdx.x;
  const int m0 = bx * 64;
  const int tcol = t & 15, trow = t >> 4;
  int dn = 0;
  #pragma unroll
  for (int j = 0; j < 4; ++j)
    if (j < it) dn |= (diffsq[j * GG + g] < CONV_TH2) ? 1 : 0;
  float diffp = 0.f;
  #pragma unroll
  for (int p = 0; p < 4; ++p) {
    int ml = p * 16 + trow;
    size_t off = (size_t)(m0 + ml) * 256 + g * 64 + tcol * 4;
    float4 s  = *(const float4*)(Cp + off);
    float4 q1 = *(const float4*)(Cp + (size_t)1 * NN * 256 + off);
    float4 q2 = *(const float4*)(Cp + (size_t)2 * NN * 256 + off);
    float4 q3 = *(const float4*)(Cp + (size_t)3 * NN * 256 + off);
    s.x += q1.x + q2.x + q3.x; s.y += q1.y + q2.y + q3.y;
    s.z += q1.z + q2.z + q3.z; s.w += q1.w + q2.w + q3.w;
    float4 wv = *(const float4*)(wiu + off);
    float4 old = *(const float4*)(hx + off);
    float4 nv;
    nv.x = tanhf(wv.x + s.x); nv.y = tanhf(wv.y + s.y);
    nv.z = tanhf(wv.z + s.z); nv.w = tanhf(wv.w + s.w);
    float4 ov;
    ov.x = dn ? old.x : nv.x; ov.y = dn ? old.y : nv.y;
    ov.z = dn ? old.z : nv.z; ov.w = dn ? old.w : nv.w;
    *(float4*)(hx + off) = ov;
    float dx = nv.x - old.x, dy = nv.y - old.y, dz = nv.z - old.z, dw = nv.w - old.w;
    diffp += dx * dx + dy * dy + dz * dz + dw * dw;
    hxs[ml * 65 + tcol * 4 + 0] = ov.x;
    hxs[ml * 65 + tcol * 4 + 1] = ov.y;
    hxs[ml * 65 + tcol * 4 + 2] = ov.z;
    hxs[ml * 65 + tcol * 4 + 3] = ov.w;
  }
  if (write_lin) {
    #pragma unroll
    for (int p = 0; p < 16; ++p) {
      int idx = p * 256 + t;
      Whs[(idx >> 6) * 65 + (idx & 63)] = Whh[(size_t)g * HH * HH + idx];
    }
  }
  for (int o = 32; o; o >>= 1) diffp += __shfl_down(diffp, o);
  if ((t & 63) == 0) atomicAdd(diffsq + it * GG + g, diffp);
  if (!write_lin) return;
  __syncthreads();
  const int ml = t & 63, wv_ = t >> 6;
  float lacc[16];
  #pragma unroll
  for (int i = 0; i < 16; ++i) lacc[i] = 0.f;
  for (int h = 0; h < 64; ++h) {
    float xh = hxs[ml * 65 + h];
    #pragma unroll
    for (int i = 0; i < 16; ++i)
      lacc[i] += xh * Whs[(wv_ + 4 * i) * 65 + h];
  }
  #pragma unroll
  for (int i = 0; i < 16; ++i)
    lin_t[(size_t)(g * 64 + wv_ + 4 * i) * NN + m0 + ml] = (_Float16)lacc[i];
}

extern "C" void kernel_launch(void* const* d_in, const int* in_sizes, int n_in,
                              void* d_out, int out_size, void* d_ws, size_t ws_size,
                              hipStream_t stream) {
  const float* X   = (const float*)d_in[0];
  const float* L   = (const float*)d_in[1];
  const float* Wih = (const float*)d_in[2];
  const float* Whh = (const float*)d_in[3];
  float* out = (float*)d_out;
  char* ws = (char*)d_ws;
  _Float16* Lh    = (_Float16*)ws;
  float*    wiu   = (float*)(ws + OFF_WIU);
  _Float16* lin_t = (_Float16*)(ws + OFF_LIN);
  float*    Cp    = (float*)(ws + OFF_CP);
  float*    diffsq = (float*)(ws + OFF_META);

  k_convert<<<32768, 256, 0, stream>>>(L, Lh, diffsq);
  k_wiu<<<dim3(128, 4), 256, 0, stream>>>(X, Wih, Whh, wiu, out, lin_t, diffsq);
  for (int it = 1; it <= 4; ++it) {
    k_gemm<<<dim3(64, 4), 512, 0, stream>>>(Lh, lin_t, Cp);
    k_post<<<dim3(128, 4), 256, 0, stream>>>(Cp, wiu, Whh, out, lin_t, diffsq,
                                             it, (it < 4) ? 1 : 0);
  }
}